// Round 14
// baseline (474.347 us; speedup 1.0000x reference)
//
#include <hip/hip_runtime.h>
#include <hip/hip_bf16.h>

#define NNODE 100000
#define EDG   500000
#define DD    128
#define FF    64
#define NCLS  5

// ws layout (ushort units). Weights bf16 ROW-MAJOR (A-operand of transposed
// GEMMs: D^T[m=outfeat][n=edge] = W[m][k] * ACT[n][k]).
#define OFF_W1   0                       // [128][64]
#define OFF_W2   8192                    // [128][128]
#define OFF_W3   24576
#define OFF_WCR  40960
#define OFF_WCL  57344
#define OFF_P0   73728
#define OFF_P1   90112
#define OFF_HU   106496                  // [NNODE][128] bf16
#define OFF_HV   (106496 + NNODE * DD)
#define PREP_TOT 106496

typedef __attribute__((ext_vector_type(8))) short short8;
typedef __attribute__((ext_vector_type(4))) float f32x4;

union U4 { uint4 v; ushort s[8]; };
union U2 { uint2 v; ushort s[4]; };

__device__ __forceinline__ float bf2f(ushort u) {
  return __uint_as_float(((unsigned int)u) << 16);
}
__device__ __forceinline__ ushort f2bf(float f) {
  unsigned int u = __float_as_uint(f);
  u += 0x7FFF + ((u >> 16) & 1);
  return (ushort)(u >> 16);
}
__device__ __forceinline__ ushort2 pk2(float a, float b) {
  __hip_bfloat162 t = __float22bfloat162_rn(make_float2(a, b));
  return *(ushort2*)&t;
}
__device__ __forceinline__ ushort4 pk4(float a, float b, float c, float d) {
  ushort2 lo = pk2(a, b), hi = pk2(c, d);
  ushort4 o; o.x = lo.x; o.y = lo.y; o.z = hi.x; o.w = hi.y; return o;
}

// XOR-swizzled LDS addressing (rows = 128 ushorts = 256 B; 16B granule index
// XORed with row&7). col%4==0 required.
__device__ __forceinline__ int sw(int row, int col) {
  return row * 128 + ((((col >> 3) ^ (row & 7)) << 3) | (col & 7));
}

// Ledger: R6 reg-hoisted weights -> spill (WRITE 212 MB). R9 deep reg
// prefetch -> scratch demotion (WRITE 360 MB). R10 thin waves: occupancy
// 42->64.5%, dur unchanged -> not latency-bound. R11 128-edge tile: 252->224
// (-11%); pipes now collectively ~85% busy (VALU 27 + MFMA 17 + LDS ~40) ->
// work-bound. R12: remove work -- ec stays in f32 accumulator (C-layout ==
// dot layout), U never touches LDS, V built in-register from acc+hv frag
// gathers; P-GEMM split in halves to cap VGPR. Barriers 9->6, -192KB
// LDS/block, -2 VALU pack passes.

// Thin transposed GEMM over NT 16-edge tiles: wave owns feats [m0,m0+16).
template <int NT>
__device__ __forceinline__ void gemm_T1(const ushort* act,
                                        const ushort* __restrict__ W, int K,
                                        int ksteps, f32x4 acc[NT],
                                        int m0, int l15, int q) {
  for (int ks = 0; ks < ksteps; ++ks) {
    const int ko = ks * 32 + q * 8;
    short8 a0 = *(const short8*)(W + (m0 + l15) * K + ko);
#pragma unroll
    for (int nt = 0; nt < NT; ++nt) {
      short8 b = *(const short8*)&act[sw(nt * 16 + l15, ko)];
      acc[nt] = __builtin_amdgcn_mfma_f32_16x16x32_bf16(a0, b, acc[nt], 0, 0, 0);
    }
  }
}

template <int NT>
__device__ __forceinline__ void zaccN(f32x4 a[NT]) {
#pragma unroll
  for (int j = 0; j < NT; ++j) a[j] = (f32x4){0.f, 0.f, 0.f, 0.f};
}

// D^T C-layout: lane = edge nt*16+l15, 4 contiguous feats m0+q*4+r.
template <int NT>
__device__ __forceinline__ void store_T1(ushort* dst, f32x4 acc[NT],
                                         const float* __restrict__ bias, int relu,
                                         int m0, int l15, int q) {
  const int feat = m0 + q * 4;
  float4 bv = bias ? *(const float4*)(bias + feat) : make_float4(0.f, 0.f, 0.f, 0.f);
#pragma unroll
  for (int nt = 0; nt < NT; ++nt) {
    const int edge = nt * 16 + l15;
    float v0 = acc[nt][0] + bv.x, v1 = acc[nt][1] + bv.y;
    float v2 = acc[nt][2] + bv.z, v3 = acc[nt][3] + bv.w;
    if (relu) {
      v0 = fmaxf(v0, 0.f); v1 = fmaxf(v1, 0.f);
      v2 = fmaxf(v2, 0.f); v3 = fmaxf(v3, 0.f);
    }
    *(ushort4*)&dst[sw(edge, feat)] = pk4(v0, v1, v2, v3);
  }
}

// ---------------- prep: bf16 row-major weight copies ----------------------
__global__ void __launch_bounds__(256) prep_kernel(
    const float* __restrict__ W1, const float* __restrict__ W2,
    const float* __restrict__ W3, const float* __restrict__ W_comb,
    const float* __restrict__ P, ushort* __restrict__ ws) {
  int idx = blockIdx.x * 256 + threadIdx.x;
  if (idx >= PREP_TOT) return;
  float val;
  if (idx < 8192) {
    val = W1[idx];
  } else {
    int r = idx - 8192, m = r >> 14, rr = r & 16383;
    switch (m) {
      case 0:  val = W2[rr]; break;
      case 1:  val = W3[rr]; break;
      case 2:  { int n = rr >> 7, k = rr & 127; val = W_comb[n * 256 + 128 + k]; } break;
      case 3:  { int n = rr >> 7, k = rr & 127; val = W_comb[n * 256 + k]; } break;
      case 4:  val = P[rr]; break;
      default: val = P[16384 + rr]; break;
    }
  }
  ws[idx] = f2bf(val);
}

// ---------------- node kernel: hu/hv = h @ Wcl^T --------------------------
// 128 rows / 512 threads / ~64 KB LDS. (Unchanged from R11.)
__global__ void __launch_bounds__(512, 4) node_kernel(
    const float* __restrict__ h_src, const float* __restrict__ h_dst,
    ushort* __restrict__ ws) {
  __shared__ ushort BUF[2][128][128];
  ushort* A = &BUF[0][0][0];
  ushort* B = &BUF[1][0][0];
  const int NTIL = (NNODE + 127) / 128;
  const int tid = threadIdx.x;
  const int lane = tid & 63, l15 = lane & 15, q = lane >> 4;
  const int m0 = (tid >> 6) * 16;
  const int bb = blockIdx.x;
  const float* h = (bb < NTIL) ? h_src : h_dst;
  ushort* op = ws + ((bb < NTIL) ? OFF_HU : OFF_HV);
  const int r0 = ((bb < NTIL) ? bb : bb - NTIL) * 128;
  const int srow = tid >> 2, part = tid & 3;
  int row = r0 + srow; if (row >= NNODE) row = NNODE - 1;
  {
    const float4* src = (const float4*)(h + (long)row * DD) + part * 8;
#pragma unroll
    for (int c = 0; c < 4; ++c) {
      float4 v0 = src[c * 2], v1 = src[c * 2 + 1];
      U4 o;
      *(ushort4*)&o.s[0] = pk4(v0.x, v0.y, v0.z, v0.w);
      *(ushort4*)&o.s[4] = pk4(v1.x, v1.y, v1.z, v1.w);
      *(uint4*)&A[sw(srow, part * 32 + c * 8)] = o.v;
    }
  }
  __syncthreads();
  f32x4 acc[8];
  zaccN<8>(acc);
  gemm_T1<8>(A, ws + OFF_WCL, 128, 4, acc, m0, l15, q);
  store_T1<8>(B, acc, nullptr, 0, m0, l15, q);
  __syncthreads();
  if (r0 + srow < NNODE) {
    uint4* d = (uint4*)(op + (long)(r0 + srow) * DD + part * 32);
#pragma unroll
    for (int i = 0; i < 4; ++i)
      d[i] = *(const uint4*)&B[sw(srow, part * 32 + i * 8)];
  }
}

// ---------------- fused edge kernel: 128 edges / 8 waves, 6 barriers ------
// ec lives in the f32 MFMA accumulator (C-layout == dot layout):
//   V = acc + hv_frag -> packed once to LDS (P-GEMM B-operand)
//   U = acc + hu_frag -> stays in registers; dot is pure register FMA.
// hv/hu fragments gathered per-lane (8 B, L3-resident tables) under the
// e3/ec GEMMs. P-GEMM split in nt-halves to keep tacc at 32 regs.
__global__ void __launch_bounds__(512, 4) edge_kernel(
    const float* __restrict__ efeats, const int* __restrict__ u_idx,
    const int* __restrict__ v_idx, const float* __restrict__ b1,
    const float* __restrict__ b2, const float* __restrict__ b3,
    const float* __restrict__ W_cb, const ushort* __restrict__ ws,
    float* __restrict__ out) {
  __shared__ ushort BUF[2][128][128];
  __shared__ float OB[128][2];
  ushort* A = &BUF[0][0][0];
  ushort* B = &BUF[1][0][0];

  const int tid = threadIdx.x;
  const int lane = tid & 63;
  const int l15 = lane & 15, q = lane >> 4;
  const int m0 = (tid >> 6) * 16;
  const long e0 = (long)blockIdx.x * 128;

  const int srow = tid >> 2, part = tid & 3;
  long grow = e0 + srow; if (grow >= EDG) grow = EDG - 1;

  // stage X -> A  [128 edges][64 feats]
  {
    const float4* src = (const float4*)(efeats + grow * FF) + part * 4;
#pragma unroll
    for (int c = 0; c < 2; ++c) {
      float4 v0 = src[c * 2], v1 = src[c * 2 + 1];
      U4 o;
      *(ushort4*)&o.s[0] = pk4(v0.x, v0.y, v0.z, v0.w);
      *(ushort4*)&o.s[4] = pk4(v1.x, v1.y, v1.z, v1.w);
      *(uint4*)&A[sw(srow, part * 16 + c * 8)] = o.v;
    }
  }
  __syncthreads();                                    // 1

  f32x4 acc[8];
  // e1 = relu(X@W1^T+b1): A -> B
  zaccN<8>(acc); gemm_T1<8>(A, ws + OFF_W1, 64, 2, acc, m0, l15, q);
  store_T1<8>(B, acc, b1, 1, m0, l15, q);
  __syncthreads();                                    // 2
  // e2: B -> A
  zaccN<8>(acc); gemm_T1<8>(B, ws + OFF_W2, 128, 4, acc, m0, l15, q);
  store_T1<8>(A, acc, b2, 1, m0, l15, q);
  __syncthreads();                                    // 3

  // per-lane endpoint indices (latency hidden under e3 GEMM)
  int vidx[8], uidx[8];
#pragma unroll
  for (int nt = 0; nt < 8; ++nt) {
    long g = e0 + nt * 16 + l15; if (g >= EDG) g = EDG - 1;
    vidx[nt] = v_idx[g]; uidx[nt] = u_idx[g];
  }

  // e3: A -> B
  zaccN<8>(acc); gemm_T1<8>(A, ws + OFF_W3, 128, 4, acc, m0, l15, q);
  store_T1<8>(B, acc, b3, 0, m0, l15, q);
  __syncthreads();                                    // 4

  // hv/hu fragment gathers (8 B per edge, C-layout; hidden under ec GEMM)
  U2 hvf[8], huf[8];
#pragma unroll
  for (int nt = 0; nt < 8; ++nt) {
    hvf[nt].v = *(const uint2*)(ws + OFF_HV + (long)vidx[nt] * DD + m0 + q * 4);
    huf[nt].v = *(const uint2*)(ws + OFF_HU + (long)uidx[nt] * DD + m0 + q * 4);
  }

  // ec = e3@Wcr^T: B -> acc (f32, stays in registers)
  zaccN<8>(acc); gemm_T1<8>(B, ws + OFF_WCR, 128, 4, acc, m0, l15, q);

  // V = acc + hv -> A (bf16, P-GEMM operand); U = acc + hu stays in regs
#pragma unroll
  for (int nt = 0; nt < 8; ++nt) {
    const int edge = nt * 16 + l15;
    float v0 = acc[nt][0] + bf2f(hvf[nt].s[0]);
    float v1 = acc[nt][1] + bf2f(hvf[nt].s[1]);
    float v2 = acc[nt][2] + bf2f(hvf[nt].s[2]);
    float v3 = acc[nt][3] + bf2f(hvf[nt].s[3]);
    *(ushort4*)&A[sw(edge, m0 + q * 4)] = pk4(v0, v1, v2, v3);
    acc[nt][0] += bf2f(huf[nt].s[0]);
    acc[nt][1] += bf2f(huf[nt].s[1]);
    acc[nt][2] += bf2f(huf[nt].s[2]);
    acc[nt][3] += bf2f(huf[nt].s[3]);
  }
  if (tid < 256) OB[tid >> 1][tid & 1] = 0.f;
  __syncthreads();                                    // 5

  // T_b = V @ P_b^T in nt-halves (tacc 32 regs); dot vs U (regs) fused
#pragma unroll
  for (int h = 0; h < 2; ++h) {
    f32x4 t0[4], t1[4];
    zaccN<4>(t0); zaccN<4>(t1);
    for (int ks = 0; ks < 4; ++ks) {
      const int ko = ks * 32 + q * 8;
      short8 a0 = *(const short8*)(ws + OFF_P0 + (m0 + l15) * 128 + ko);
      short8 a1 = *(const short8*)(ws + OFF_P1 + (m0 + l15) * 128 + ko);
#pragma unroll
      for (int j = 0; j < 4; ++j) {
        short8 b = *(const short8*)&A[sw((h * 4 + j) * 16 + l15, ko)];
        t0[j] = __builtin_amdgcn_mfma_f32_16x16x32_bf16(a0, b, t0[j], 0, 0, 0);
        t1[j] = __builtin_amdgcn_mfma_f32_16x16x32_bf16(a1, b, t1[j], 0, 0, 0);
      }
    }
#pragma unroll
    for (int j = 0; j < 4; ++j) {
      const int nt = h * 4 + j;
      const int edge = nt * 16 + l15;
      float pb0 = t0[j][0] * acc[nt][0] + t0[j][1] * acc[nt][1]
                + t0[j][2] * acc[nt][2] + t0[j][3] * acc[nt][3];
      float pb1 = t1[j][0] * acc[nt][0] + t1[j][1] * acc[nt][1]
                + t1[j][2] * acc[nt][2] + t1[j][3] * acc[nt][3];
      pb0 += __shfl_xor(pb0, 16, 64); pb0 += __shfl_xor(pb0, 32, 64);
      pb1 += __shfl_xor(pb1, 16, 64); pb1 += __shfl_xor(pb1, 32, 64);
      if (q == 0) {
        atomicAdd(&OB[edge][0], pb0);
        atomicAdd(&OB[edge][1], pb1);
      }
    }
  }
  __syncthreads();                                    // 6

  for (int t = tid; t < 128 * NCLS; t += 512) {
    int r = t / NCLS, c = t % NCLS;
    long erow = e0 + r;
    if (erow < EDG) {
      out[erow * NCLS + c] = OB[r][0] * W_cb[c * 2] + OB[r][1] * W_cb[c * 2 + 1];
    }
  }
}

extern "C" void kernel_launch(void* const* d_in, const int* in_sizes, int n_in,
                              void* d_out, int out_size, void* d_ws,
                              size_t ws_size, hipStream_t stream) {
  const float* h_src  = (const float*)d_in[0];
  const float* h_dst  = (const float*)d_in[1];
  const float* efeats = (const float*)d_in[2];
  const int*   u_idx  = (const int*)d_in[3];
  const int*   v_idx  = (const int*)d_in[4];
  const float* W1     = (const float*)d_in[5];
  const float* b1     = (const float*)d_in[6];
  const float* W2     = (const float*)d_in[7];
  const float* b2     = (const float*)d_in[8];
  const float* W3     = (const float*)d_in[9];
  const float* b3     = (const float*)d_in[10];
  const float* W_comb = (const float*)d_in[11];
  const float* P      = (const float*)d_in[12];
  const float* W_cb   = (const float*)d_in[13];
  ushort* ws = (ushort*)d_ws;
  float* out = (float*)d_out;

  prep_kernel<<<(PREP_TOT + 255) / 256, 256, 0, stream>>>(W1, W2, W3, W_comb, P, ws);
  node_kernel<<<2 * ((NNODE + 127) / 128), 512, 0, stream>>>(h_src, h_dst, ws);
  edge_kernel<<<(EDG + 127) / 128, 512, 0, stream>>>(efeats, u_idx, v_idx,
                                                     b1, b2, b3, W_cb, ws, out);
}